// Round 7
// baseline (926.037 us; speedup 1.0000x reference)
//
#include <hip/hip_runtime.h>

#define N_NODES 100000
#define N_EDGES 600000
#define EPS_BN 1e-5f
#define EPS_NORM 1e-12f

// ===========================================================================
// CSR build: degree histogram -> exclusive scan -> cursor fill
// ===========================================================================
__global__ void k_deg(const int* __restrict__ dst, int* __restrict__ deg, int E) {
    int e = blockIdx.x * blockDim.x + threadIdx.x;
    if (e < E) atomicAdd(&deg[dst[e]], 1);
}

__global__ void k_scan1(const int* __restrict__ in, int* __restrict__ out,
                        int* __restrict__ bsum, int n) {
    __shared__ int s[256];
    int i = blockIdx.x * 256 + threadIdx.x;
    int v = (i < n) ? in[i] : 0;
    s[threadIdx.x] = v;
    __syncthreads();
#pragma unroll
    for (int off = 1; off < 256; off <<= 1) {
        int t = (threadIdx.x >= off) ? s[threadIdx.x - off] : 0;
        __syncthreads();
        s[threadIdx.x] += t;
        __syncthreads();
    }
    if (i < n) out[i] = s[threadIdx.x] - v;
    if (threadIdx.x == 255) bsum[blockIdx.x] = s[255];
}

__global__ void k_scan2(int* __restrict__ bsum, int nb) {
    __shared__ int s[512];
    int v = (threadIdx.x < nb) ? bsum[threadIdx.x] : 0;
    s[threadIdx.x] = v;
    __syncthreads();
#pragma unroll
    for (int off = 1; off < 512; off <<= 1) {
        int t = (threadIdx.x >= off) ? s[threadIdx.x - off] : 0;
        __syncthreads();
        s[threadIdx.x] += t;
        __syncthreads();
    }
    if (threadIdx.x < nb) bsum[threadIdx.x] = s[threadIdx.x] - v;
}

__global__ void k_prep(int* __restrict__ offs, const int* __restrict__ bsum,
                       const int* __restrict__ deg, int* __restrict__ cursor,
                       float* __restrict__ inv, int n, int E) {
    int i = blockIdx.x * 256 + threadIdx.x;
    if (i >= n) return;
    int o = offs[i] + bsum[i >> 8];
    offs[i] = o;
    cursor[i] = o;
    inv[i] = 1.0f / fmaxf((float)deg[i], 1.0f);
    if (i == 0) offs[n] = E;
}

__global__ void k_fill(const int* __restrict__ src, const int* __restrict__ dst,
                       int* __restrict__ cursor, int* __restrict__ adj, int E) {
    int e = blockIdx.x * blockDim.x + threadIdx.x;
    if (e < E) {
        int pos = atomicAdd(&cursor[dst[e]], 1);
        adj[pos] = src[e];
    }
}

// ===========================================================================
// Gather-aggregate (mean): one 64-lane wave per node, unroll x4 for MLP.
// ===========================================================================
__global__ void k_gather10(const float* __restrict__ h, const int* __restrict__ adj,
                           const int* __restrict__ offs, const float* __restrict__ inv,
                           float* __restrict__ mean, int n) {
    int node = (blockIdx.x * blockDim.x + threadIdx.x) >> 6;
    int lane = threadIdx.x & 63;
    if (node >= n) return;
    int beg = offs[node], end = offs[node + 1];
    float iv = inv[node];
    float acc = 0.0f;
    for (int p = beg; p < end; ++p) {
        int s = adj[p];
        if (lane < 10) acc += h[(size_t)s * 10 + lane];
    }
    if (lane < 10) mean[(size_t)node * 10 + lane] = acc * iv;
}

__global__ void k_gather64(const float* __restrict__ h, const int* __restrict__ adj,
                           const int* __restrict__ offs, const float* __restrict__ inv,
                           float* __restrict__ mean, int n) {
    int node = (blockIdx.x * blockDim.x + threadIdx.x) >> 6;
    int lane = threadIdx.x & 63;
    if (node >= n) return;
    int beg = offs[node], end = offs[node + 1];
    float iv = inv[node];
    float a0 = 0.0f, a1 = 0.0f, a2 = 0.0f, a3 = 0.0f;
    int p = beg;
    for (; p + 4 <= end; p += 4) {
        int s0 = adj[p], s1 = adj[p + 1], s2 = adj[p + 2], s3 = adj[p + 3];
        a0 += h[(size_t)s0 * 64 + lane];
        a1 += h[(size_t)s1 * 64 + lane];
        a2 += h[(size_t)s2 * 64 + lane];
        a3 += h[(size_t)s3 * 64 + lane];
    }
    for (; p < end; ++p) a0 += h[(size_t)adj[p] * 64 + lane];
    mean[(size_t)node * 64 + lane] = ((a0 + a1) + (a2 + a3)) * iv;
}

__global__ void k_gather128(const float* __restrict__ h, const int* __restrict__ adj,
                            const int* __restrict__ offs, const float* __restrict__ inv,
                            float* __restrict__ mean, int n) {
    int node = (blockIdx.x * blockDim.x + threadIdx.x) >> 6;
    int lane = threadIdx.x & 63;
    if (node >= n) return;
    int beg = offs[node], end = offs[node + 1];
    float iv = inv[node];
    float2 a0 = {0, 0}, a1 = {0, 0}, a2 = {0, 0}, a3 = {0, 0};
    int p = beg;
    for (; p + 4 <= end; p += 4) {
        int s0 = adj[p], s1 = adj[p + 1], s2 = adj[p + 2], s3 = adj[p + 3];
        float2 v0 = *(const float2*)&h[(size_t)s0 * 128 + lane * 2];
        float2 v1 = *(const float2*)&h[(size_t)s1 * 128 + lane * 2];
        float2 v2 = *(const float2*)&h[(size_t)s2 * 128 + lane * 2];
        float2 v3 = *(const float2*)&h[(size_t)s3 * 128 + lane * 2];
        a0.x += v0.x; a0.y += v0.y;
        a1.x += v1.x; a1.y += v1.y;
        a2.x += v2.x; a2.y += v2.y;
        a3.x += v3.x; a3.y += v3.y;
    }
    for (; p < end; ++p) {
        float2 v0 = *(const float2*)&h[(size_t)adj[p] * 128 + lane * 2];
        a0.x += v0.x; a0.y += v0.y;
    }
    float2 o = {((a0.x + a1.x) + (a2.x + a3.x)) * iv,
                ((a0.y + a1.y) + (a2.y + a3.y)) * iv};
    *(float2*)&mean[(size_t)node * 128 + lane * 2] = o;
}

// ===========================================================================
// Simple linear (layer 1: DIN=10, DOUT=64). mean already divided.
// ===========================================================================
template <int DIN, int DOUT, bool RELU>
__global__ void k_linear(const float* __restrict__ h, const float* __restrict__ mean,
                         const float* __restrict__ Wl, const float* __restrict__ Wr,
                         const float* __restrict__ bias,
                         const float* __restrict__ bn_g, const float* __restrict__ bn_b,
                         const float* __restrict__ bn_m, const float* __restrict__ bn_v,
                         float* __restrict__ out, int n) {
    int tid = blockIdx.x * blockDim.x + threadIdx.x;
    int node = tid / DOUT;
    int c = tid - node * DOUT;
    if (node >= n) return;

    const float* hr = h + (size_t)node * DIN;
    const float* mr = mean + (size_t)node * DIN;

    float acc = bias[c];
#pragma unroll
    for (int k = 0; k < DIN; ++k) {
        acc += mr[k] * Wl[k * DOUT + c] + hr[k] * Wr[k * DOUT + c];
    }
    float o = (acc - bn_m[c]) * rsqrtf(bn_v[c] + EPS_BN) * bn_g[c] + bn_b[c];
    if (RELU) o = fmaxf(o, 0.0f);
    out[(size_t)node * DOUT + c] = o;
}

// ===========================================================================
// Broadcast-data linear+BN(+ReLU), DOUT=128. NO LDS, NO barriers.
// Mapping: lane <-> channel pair (c=2*lane: weight float2 loads perfectly
// coalesced, pipelined on vmcnt); wave <-> 8 private nodes (acc = 8n x 2c).
// mean/h read as wave-uniform-address dwordx4 loads -> 1 line/request,
// L1-hit on subsequent kg (rows sequential). Per kg (4 k): 24 VMEM + 64 FMA.
// All latency rides vmcnt; 4 waves/SIMD hide it. Grid: n/32 blocks (exact
// for n=100000).
// ===========================================================================
template <int DIN, bool RELU>
__global__ __launch_bounds__(256) void k_linear_bc(
    const float* __restrict__ h, const float* __restrict__ mean,
    const float* __restrict__ Wl, const float* __restrict__ Wr,
    const float* __restrict__ bias,
    const float* __restrict__ bn_g, const float* __restrict__ bn_b,
    const float* __restrict__ bn_m, const float* __restrict__ bn_v,
    float* __restrict__ out, int n) {
    constexpr int DOUT = 128;
    const int lane = threadIdx.x & 63;
    const int wv = threadIdx.x >> 6;
    const int node0 = (blockIdx.x * 4 + wv) * 8;
    const int c0 = lane * 2;
    if (node0 >= n) return;

    float acc0[8], acc1[8];
#pragma unroll
    for (int i = 0; i < 8; ++i) { acc0[i] = 0.0f; acc1[i] = 0.0f; }

    const int nmax = n - 1;

#pragma unroll 1
    for (int kg = 0; kg < DIN / 4; ++kg) {
        float mv[8][4], hv[8][4];
#pragma unroll
        for (int nd = 0; nd < 8; ++nd) {
            int gn = node0 + nd;
            if (gn > nmax) gn = nmax;
            size_t base = (size_t)gn * DIN + kg * 4;
            float4 m4 = *(const float4*)&mean[base];
            float4 h4 = *(const float4*)&h[base];
            mv[nd][0] = m4.x; mv[nd][1] = m4.y; mv[nd][2] = m4.z; mv[nd][3] = m4.w;
            hv[nd][0] = h4.x; hv[nd][1] = h4.y; hv[nd][2] = h4.z; hv[nd][3] = h4.w;
        }
        float2 wl[4], wr[4];
#pragma unroll
        for (int j = 0; j < 4; ++j) {
            wl[j] = *(const float2*)&Wl[(size_t)(kg * 4 + j) * DOUT + c0];
            wr[j] = *(const float2*)&Wr[(size_t)(kg * 4 + j) * DOUT + c0];
        }
#pragma unroll
        for (int j = 0; j < 4; ++j) {
#pragma unroll
            for (int nd = 0; nd < 8; ++nd) {
                acc0[nd] = fmaf(mv[nd][j], wl[j].x, fmaf(hv[nd][j], wr[j].x, acc0[nd]));
                acc1[nd] = fmaf(mv[nd][j], wl[j].y, fmaf(hv[nd][j], wr[j].y, acc1[nd]));
            }
        }
    }

    // ---- epilogue: bias+BN folded, per-lane channel pair ----
    float A0 = bn_g[c0] * rsqrtf(bn_v[c0] + EPS_BN);
    float C0 = (bias[c0] - bn_m[c0]) * A0 + bn_b[c0];
    float A1 = bn_g[c0 + 1] * rsqrtf(bn_v[c0 + 1] + EPS_BN);
    float C1 = (bias[c0 + 1] - bn_m[c0 + 1]) * A1 + bn_b[c0 + 1];

#pragma unroll
    for (int nd = 0; nd < 8; ++nd) {
        int gn = node0 + nd;
        if (gn >= n) break;
        float v0 = acc0[nd] * A0 + C0;
        float v1 = acc1[nd] * A1 + C1;
        if (RELU) { v0 = fmaxf(v0, 0.0f); v1 = fmaxf(v1, 0.0f); }
        float2 o = {v0, v1};
        *(float2*)&out[(size_t)gn * DOUT + c0] = o;
    }
}

// ===========================================================================
// L2-normalize + logits (one wave per node)
// ===========================================================================
__global__ void k_norm_logits(float* __restrict__ emb, float* __restrict__ logits,
                              const float* __restrict__ Wc, const float* __restrict__ bc,
                              int n) {
    int gtid = blockIdx.x * blockDim.x + threadIdx.x;
    int node = gtid >> 6;
    int lane = threadIdx.x & 63;
    if (node >= n) return;

    float* row = emb + (size_t)node * 128;
    float a = row[lane];
    float b = row[lane + 64];

    float ss = a * a + b * b;
#pragma unroll
    for (int off = 32; off; off >>= 1) ss += __shfl_down(ss, off, 64);
    ss = __shfl(ss, 0, 64);

    float inv = 1.0f / fmaxf(sqrtf(ss), EPS_NORM);
    a *= inv;
    b *= inv;
    row[lane] = a;
    row[lane + 64] = b;

    float l0 = a * Wc[lane * 2 + 0] + b * Wc[(lane + 64) * 2 + 0];
    float l1 = a * Wc[lane * 2 + 1] + b * Wc[(lane + 64) * 2 + 1];
#pragma unroll
    for (int off = 32; off; off >>= 1) {
        l0 += __shfl_down(l0, off, 64);
        l1 += __shfl_down(l1, off, 64);
    }
    if (lane == 0) {
        logits[(size_t)node * 2 + 0] = l0 + bc[0];
        logits[(size_t)node * 2 + 1] = l1 + bc[1];
    }
}

// ===========================================================================
extern "C" void kernel_launch(void* const* d_in, const int* in_sizes, int n_in,
                              void* d_out, int out_size, void* d_ws, size_t ws_size,
                              hipStream_t stream) {
    const float* x    = (const float*)d_in[0];
    const int*   ei   = (const int*)d_in[1];
    const int*   src  = ei;
    const int*   dstp = ei + N_EDGES;

    const float* W1l = (const float*)d_in[2];
    const float* W1r = (const float*)d_in[3];
    const float* b1  = (const float*)d_in[4];
    const float* g1  = (const float*)d_in[5];
    const float* bb1 = (const float*)d_in[6];
    const float* m1  = (const float*)d_in[7];
    const float* v1  = (const float*)d_in[8];

    const float* W2l = (const float*)d_in[9];
    const float* W2r = (const float*)d_in[10];
    const float* b2  = (const float*)d_in[11];
    const float* g2  = (const float*)d_in[12];
    const float* bb2 = (const float*)d_in[13];
    const float* m2  = (const float*)d_in[14];
    const float* v2  = (const float*)d_in[15];

    const float* W3l = (const float*)d_in[16];
    const float* W3r = (const float*)d_in[17];
    const float* b3  = (const float*)d_in[18];
    const float* g3  = (const float*)d_in[19];
    const float* bb3 = (const float*)d_in[20];
    const float* m3  = (const float*)d_in[21];
    const float* v3  = (const float*)d_in[22];

    const float* Wc = (const float*)d_in[23];
    const float* bc = (const float*)d_in[24];

    // workspace layout (all 4-byte elements)
    float* inv   = (float*)d_ws;                        // N
    int*   deg   = (int*)(inv + N_NODES);               // N
    int*   offs  = deg + N_NODES;                       // N+1
    int*   cursor= offs + N_NODES + 1;                  // N
    int*   adj   = cursor + N_NODES;                    // E
    int*   bsum  = adj + N_EDGES;                       // 512
    float* agg   = (float*)(bsum + 512);                // N*128 (mean buffer)
    float* h1    = agg + (size_t)N_NODES * 128;         // N*64
    float* h2    = h1 + (size_t)N_NODES * 64;           // N*128

    float* emb    = (float*)d_out;
    float* logits = emb + (size_t)N_NODES * 128;

    const int B = 256;
    const int nb = (N_NODES + 255) / 256;               // 391 <= 512
    const int nBcBlocks = (N_NODES + 31) / 32;          // 3125 (exact)
    const int nWaveBlocks = ((size_t)N_NODES * 64 + B - 1) / B;

    // ---- CSR build ----
    hipMemsetAsync(deg, 0, N_NODES * sizeof(int), stream);
    k_deg<<<(N_EDGES + B - 1) / B, B, 0, stream>>>(dstp, deg, N_EDGES);
    k_scan1<<<nb, 256, 0, stream>>>(deg, offs, bsum, N_NODES);
    k_scan2<<<1, 512, 0, stream>>>(bsum, nb);
    k_prep<<<nb, 256, 0, stream>>>(offs, bsum, deg, cursor, inv, N_NODES, N_EDGES);
    k_fill<<<(N_EDGES + B - 1) / B, B, 0, stream>>>(src, dstp, cursor, adj, N_EDGES);

    // ---- layer 1: 10 -> 64, ReLU ----
    k_gather10<<<nWaveBlocks, B, 0, stream>>>(x, adj, offs, inv, agg, N_NODES);
    k_linear<10, 64, true><<<((size_t)N_NODES * 64 + B - 1) / B, B, 0, stream>>>(
        x, agg, W1l, W1r, b1, g1, bb1, m1, v1, h1, N_NODES);

    // ---- layer 2: 64 -> 128, ReLU ----
    k_gather64<<<nWaveBlocks, B, 0, stream>>>(h1, adj, offs, inv, agg, N_NODES);
    k_linear_bc<64, true><<<nBcBlocks, 256, 0, stream>>>(
        h1, agg, W2l, W2r, b2, g2, bb2, m2, v2, h2, N_NODES);

    // ---- layer 3: 128 -> 128, no ReLU, into d_out emb region ----
    k_gather128<<<nWaveBlocks, B, 0, stream>>>(h2, adj, offs, inv, agg, N_NODES);
    k_linear_bc<128, false><<<nBcBlocks, 256, 0, stream>>>(
        h2, agg, W3l, W3r, b3, g3, bb3, m3, v3, emb, N_NODES);

    // ---- normalize + logits ----
    k_norm_logits<<<nWaveBlocks, B, 0, stream>>>(emb, logits, Wc, bc, N_NODES);
}

// Round 8
// 522.593 us; speedup vs baseline: 1.7720x; 1.7720x over previous
//
#include <hip/hip_runtime.h>

#define N_NODES 100000
#define N_EDGES 600000
#define EPS_BN 1e-5f
#define EPS_NORM 1e-12f

typedef __attribute__((ext_vector_type(8))) short bf16x8;
typedef __attribute__((ext_vector_type(4))) float f32x4;

__device__ inline unsigned bf16u(float x) {
    unsigned b = __float_as_uint(x);
    return (b + 0x7FFF + ((b >> 16) & 1)) >> 16;
}
__device__ inline float bf16back(unsigned hb) { return __uint_as_float(hb << 16); }

// ===========================================================================
// CSR build: degree histogram -> exclusive scan -> cursor fill
// ===========================================================================
__global__ void k_deg(const int* __restrict__ dst, int* __restrict__ deg, int E) {
    int e = blockIdx.x * blockDim.x + threadIdx.x;
    if (e < E) atomicAdd(&deg[dst[e]], 1);
}

__global__ void k_scan1(const int* __restrict__ in, int* __restrict__ out,
                        int* __restrict__ bsum, int n) {
    __shared__ int s[256];
    int i = blockIdx.x * 256 + threadIdx.x;
    int v = (i < n) ? in[i] : 0;
    s[threadIdx.x] = v;
    __syncthreads();
#pragma unroll
    for (int off = 1; off < 256; off <<= 1) {
        int t = (threadIdx.x >= off) ? s[threadIdx.x - off] : 0;
        __syncthreads();
        s[threadIdx.x] += t;
        __syncthreads();
    }
    if (i < n) out[i] = s[threadIdx.x] - v;
    if (threadIdx.x == 255) bsum[blockIdx.x] = s[255];
}

__global__ void k_scan2(int* __restrict__ bsum, int nb) {
    __shared__ int s[512];
    int v = (threadIdx.x < nb) ? bsum[threadIdx.x] : 0;
    s[threadIdx.x] = v;
    __syncthreads();
#pragma unroll
    for (int off = 1; off < 512; off <<= 1) {
        int t = (threadIdx.x >= off) ? s[threadIdx.x - off] : 0;
        __syncthreads();
        s[threadIdx.x] += t;
        __syncthreads();
    }
    if (threadIdx.x < nb) bsum[threadIdx.x] = s[threadIdx.x] - v;
}

__global__ void k_prep(int* __restrict__ offs, const int* __restrict__ bsum,
                       const int* __restrict__ deg, int* __restrict__ cursor,
                       float* __restrict__ inv, int n, int E) {
    int i = blockIdx.x * 256 + threadIdx.x;
    if (i >= n) return;
    int o = offs[i] + bsum[i >> 8];
    offs[i] = o;
    cursor[i] = o;
    inv[i] = 1.0f / fmaxf((float)deg[i], 1.0f);
    if (i == 0) offs[n] = E;
}

__global__ void k_fill(const int* __restrict__ src, const int* __restrict__ dst,
                       int* __restrict__ cursor, int* __restrict__ adj, int E) {
    int e = blockIdx.x * blockDim.x + threadIdx.x;
    if (e < E) {
        int pos = atomicAdd(&cursor[dst[e]], 1);
        adj[pos] = src[e];
    }
}

// ===========================================================================
// Gather-aggregate (mean): one 64-lane wave per node, unroll x4 for MLP.
// ===========================================================================
__global__ void k_gather10(const float* __restrict__ h, const int* __restrict__ adj,
                           const int* __restrict__ offs, const float* __restrict__ inv,
                           float* __restrict__ mean, int n) {
    int node = (blockIdx.x * blockDim.x + threadIdx.x) >> 6;
    int lane = threadIdx.x & 63;
    if (node >= n) return;
    int beg = offs[node], end = offs[node + 1];
    float iv = inv[node];
    float acc = 0.0f;
    for (int p = beg; p < end; ++p) {
        int s = adj[p];
        if (lane < 10) acc += h[(size_t)s * 10 + lane];
    }
    if (lane < 10) mean[(size_t)node * 10 + lane] = acc * iv;
}

__global__ void k_gather64(const float* __restrict__ h, const int* __restrict__ adj,
                           const int* __restrict__ offs, const float* __restrict__ inv,
                           float* __restrict__ mean, int n) {
    int node = (blockIdx.x * blockDim.x + threadIdx.x) >> 6;
    int lane = threadIdx.x & 63;
    if (node >= n) return;
    int beg = offs[node], end = offs[node + 1];
    float iv = inv[node];
    float a0 = 0.0f, a1 = 0.0f, a2 = 0.0f, a3 = 0.0f;
    int p = beg;
    for (; p + 4 <= end; p += 4) {
        int s0 = adj[p], s1 = adj[p + 1], s2 = adj[p + 2], s3 = adj[p + 3];
        a0 += h[(size_t)s0 * 64 + lane];
        a1 += h[(size_t)s1 * 64 + lane];
        a2 += h[(size_t)s2 * 64 + lane];
        a3 += h[(size_t)s3 * 64 + lane];
    }
    for (; p < end; ++p) a0 += h[(size_t)adj[p] * 64 + lane];
    mean[(size_t)node * 64 + lane] = ((a0 + a1) + (a2 + a3)) * iv;
}

__global__ void k_gather128(const float* __restrict__ h, const int* __restrict__ adj,
                            const int* __restrict__ offs, const float* __restrict__ inv,
                            float* __restrict__ mean, int n) {
    int node = (blockIdx.x * blockDim.x + threadIdx.x) >> 6;
    int lane = threadIdx.x & 63;
    if (node >= n) return;
    int beg = offs[node], end = offs[node + 1];
    float iv = inv[node];
    float2 a0 = {0, 0}, a1 = {0, 0}, a2 = {0, 0}, a3 = {0, 0};
    int p = beg;
    for (; p + 4 <= end; p += 4) {
        int s0 = adj[p], s1 = adj[p + 1], s2 = adj[p + 2], s3 = adj[p + 3];
        float2 v0 = *(const float2*)&h[(size_t)s0 * 128 + lane * 2];
        float2 v1 = *(const float2*)&h[(size_t)s1 * 128 + lane * 2];
        float2 v2 = *(const float2*)&h[(size_t)s2 * 128 + lane * 2];
        float2 v3 = *(const float2*)&h[(size_t)s3 * 128 + lane * 2];
        a0.x += v0.x; a0.y += v0.y;
        a1.x += v1.x; a1.y += v1.y;
        a2.x += v2.x; a2.y += v2.y;
        a3.x += v3.x; a3.y += v3.y;
    }
    for (; p < end; ++p) {
        float2 v0 = *(const float2*)&h[(size_t)adj[p] * 128 + lane * 2];
        a0.x += v0.x; a0.y += v0.y;
    }
    float2 o = {((a0.x + a1.x) + (a2.x + a3.x)) * iv,
                ((a0.y + a1.y) + (a2.y + a3.y)) * iv};
    *(float2*)&mean[(size_t)node * 128 + lane * 2] = o;
}

// ===========================================================================
// Simple linear (layer 1: DIN=10, DOUT=64). mean already divided.
// ===========================================================================
template <int DIN, int DOUT, bool RELU>
__global__ void k_linear(const float* __restrict__ h, const float* __restrict__ mean,
                         const float* __restrict__ Wl, const float* __restrict__ Wr,
                         const float* __restrict__ bias,
                         const float* __restrict__ bn_g, const float* __restrict__ bn_b,
                         const float* __restrict__ bn_m, const float* __restrict__ bn_v,
                         float* __restrict__ out, int n) {
    int tid = blockIdx.x * blockDim.x + threadIdx.x;
    int node = tid / DOUT;
    int c = tid - node * DOUT;
    if (node >= n) return;

    const float* hr = h + (size_t)node * DIN;
    const float* mr = mean + (size_t)node * DIN;

    float acc = bias[c];
#pragma unroll
    for (int k = 0; k < DIN; ++k) {
        acc += mr[k] * Wl[k * DOUT + c] + hr[k] * Wr[k * DOUT + c];
    }
    float o = (acc - bn_m[c]) * rsqrtf(bn_v[c] + EPS_BN) * bn_g[c] + bn_b[c];
    if (RELU) o = fmaxf(o, 0.0f);
    out[(size_t)node * DOUT + c] = o;
}

// ===========================================================================
// Weight pre-swizzle into MFMA B-fragment order (hi/lo bf16 split).
// W = [Wl; Wr] stacked (K=2*DIN rows, 128 cols). B-frag layout for
// mfma_f32_16x16x32_bf16: lane holds n=lane&15, k=quad*8+j (j contiguous).
// wf[((ks*8+nt)*64+lane)*8+j] so the kernel loads 16 B/lane coalesced.
// ===========================================================================
template <int DIN>
__global__ void k_wprep(const float* __restrict__ Wl, const float* __restrict__ Wr,
                        unsigned short* __restrict__ wf_hi,
                        unsigned short* __restrict__ wf_lo) {
    constexpr int K = 2 * DIN;
    int t = blockIdx.x * 256 + threadIdx.x;
    if (t >= K * 128) return;
    int j = t & 7;
    int lane = (t >> 3) & 63;
    int nt = (t >> 9) & 7;
    int ks = t >> 12;
    int k = ks * 32 + (lane >> 4) * 8 + j;
    int nn = nt * 16 + (lane & 15);
    float v = (k < DIN) ? Wl[k * 128 + nn] : Wr[(k - DIN) * 128 + nn];
    unsigned hb = bf16u(v);
    float r = v - bf16back(hb);
    wf_hi[t] = (unsigned short)hb;
    wf_lo[t] = (unsigned short)bf16u(r);
}

// ===========================================================================
// MFMA linear+BN(+ReLU), DOUT=128, K=2*DIN (concat [mean,h]).
// bf16 hi/lo split: acc += Ahi*Bhi + Alo*Bhi + Ahi*Blo (lo*lo dropped,
// ~2^-18 relative). Block: 128 nodes, 4 waves; each wave: 32 nodes (2
// m-tiles) x 128 ch (8 n-tiles). A staged per 64-k chunk into LDS as bf16
// hi/lo, row pad +8 ushort -> 2-way banks (free). B-frags from pre-swizzled
// global (coalesced 16 B/lane, L2-hot). Verified layouts (m89/m120):
// A: m=lane&15,k=quad*8+j; B: n=lane&15,k=quad*8+j; C/D: col=lane&15,
// row=quad*4+reg.
// ===========================================================================
template <int DIN, bool RELU>
__global__ __launch_bounds__(256) void k_linear_mfma(
    const float* __restrict__ h, const float* __restrict__ mean,
    const unsigned short* __restrict__ wf_hi, const unsigned short* __restrict__ wf_lo,
    const float* __restrict__ bias,
    const float* __restrict__ bn_g, const float* __restrict__ bn_b,
    const float* __restrict__ bn_m, const float* __restrict__ bn_v,
    float* __restrict__ out, int n) {
    constexpr int CH = (2 * DIN) / 64;  // 64-k chunks
    __shared__ unsigned short lsH[128][72];
    __shared__ unsigned short lsL[128][72];

    const int tid = threadIdx.x;
    const int lane = tid & 63;
    const int wv = tid >> 6;
    const int quad = lane >> 4;
    const int l15 = lane & 15;
    const int node0 = blockIdx.x * 128;

    f32x4 acc[2][8];
#pragma unroll
    for (int mt = 0; mt < 2; ++mt)
#pragma unroll
        for (int nt = 0; nt < 8; ++nt) acc[mt][nt] = {0.0f, 0.0f, 0.0f, 0.0f};

    const int srow = tid >> 1;        // staged row 0..127
    const int scol = (tid & 1) * 32;  // col group

    for (int cc = 0; cc < CH; ++cc) {
        const int kbase = cc * 64;
        const float* srcp = (kbase < DIN) ? mean : h;
        const int coloff = (kbase < DIN) ? kbase : kbase - DIN;
        if (cc) __syncthreads();
        // ---- stage + fp32 -> bf16 hi/lo convert ----
        {
            int gn = node0 + srow;
            if (gn > n - 1) gn = n - 1;
            const float* rp = srcp + (size_t)gn * DIN + coloff + scol;
#pragma unroll
            for (int g = 0; g < 4; ++g) {
                float4 f0 = *(const float4*)(rp + g * 8);
                float4 f1 = *(const float4*)(rp + g * 8 + 4);
                unsigned hx = bf16u(f0.x), hy = bf16u(f0.y), hz = bf16u(f0.z), hw = bf16u(f0.w);
                unsigned gx = bf16u(f1.x), gy = bf16u(f1.y), gz = bf16u(f1.z), gw = bf16u(f1.w);
                uint4 H, L;
                H.x = hx | (hy << 16);
                H.y = hz | (hw << 16);
                H.z = gx | (gy << 16);
                H.w = gz | (gw << 16);
                L.x = bf16u(f0.x - bf16back(hx)) | (bf16u(f0.y - bf16back(hy)) << 16);
                L.y = bf16u(f0.z - bf16back(hz)) | (bf16u(f0.w - bf16back(hw)) << 16);
                L.z = bf16u(f1.x - bf16back(gx)) | (bf16u(f1.y - bf16back(gy)) << 16);
                L.w = bf16u(f1.z - bf16back(gz)) | (bf16u(f1.w - bf16back(gw)) << 16);
                *(uint4*)&lsH[srow][scol + g * 8] = H;
                *(uint4*)&lsL[srow][scol + g * 8] = L;
            }
        }
        __syncthreads();

#pragma unroll
        for (int ks = 0; ks < 2; ++ks) {
            const int ksg = cc * 2 + ks;
            bf16x8 aH[2], aL[2];
#pragma unroll
            for (int mt = 0; mt < 2; ++mt) {
                int row = wv * 32 + mt * 16 + l15;
                int col = ks * 32 + quad * 8;
                aH[mt] = *(const bf16x8*)&lsH[row][col];
                aL[mt] = *(const bf16x8*)&lsL[row][col];
            }
#pragma unroll
            for (int nt = 0; nt < 8; ++nt) {
                int wb = ((ksg * 8 + nt) * 64 + lane) * 8;
                bf16x8 bH = *(const bf16x8*)&wf_hi[wb];
                bf16x8 bL = *(const bf16x8*)&wf_lo[wb];
#pragma unroll
                for (int mt = 0; mt < 2; ++mt) {
                    acc[mt][nt] = __builtin_amdgcn_mfma_f32_16x16x32_bf16(aH[mt], bH, acc[mt][nt], 0, 0, 0);
                    acc[mt][nt] = __builtin_amdgcn_mfma_f32_16x16x32_bf16(aL[mt], bH, acc[mt][nt], 0, 0, 0);
                    acc[mt][nt] = __builtin_amdgcn_mfma_f32_16x16x32_bf16(aH[mt], bL, acc[mt][nt], 0, 0, 0);
                }
            }
        }
    }

    // ---- epilogue: bias+BN folded, C/D layout scatter ----
#pragma unroll
    for (int nt = 0; nt < 8; ++nt) {
        int c = nt * 16 + l15;
        float As = bn_g[c] * rsqrtf(bn_v[c] + EPS_BN);
        float Cs = (bias[c] - bn_m[c]) * As + bn_b[c];
#pragma unroll
        for (int mt = 0; mt < 2; ++mt) {
#pragma unroll
            for (int r = 0; r < 4; ++r) {
                int gn = node0 + wv * 32 + mt * 16 + quad * 4 + r;
                if (gn < n) {
                    float v = acc[mt][nt][r] * As + Cs;
                    if (RELU) v = fmaxf(v, 0.0f);
                    out[(size_t)gn * 128 + c] = v;
                }
            }
        }
    }
}

// ===========================================================================
// L2-normalize + logits (one wave per node)
// ===========================================================================
__global__ void k_norm_logits(float* __restrict__ emb, float* __restrict__ logits,
                              const float* __restrict__ Wc, const float* __restrict__ bc,
                              int n) {
    int gtid = blockIdx.x * blockDim.x + threadIdx.x;
    int node = gtid >> 6;
    int lane = threadIdx.x & 63;
    if (node >= n) return;

    float* row = emb + (size_t)node * 128;
    float a = row[lane];
    float b = row[lane + 64];

    float ss = a * a + b * b;
#pragma unroll
    for (int off = 32; off; off >>= 1) ss += __shfl_down(ss, off, 64);
    ss = __shfl(ss, 0, 64);

    float inv = 1.0f / fmaxf(sqrtf(ss), EPS_NORM);
    a *= inv;
    b *= inv;
    row[lane] = a;
    row[lane + 64] = b;

    float l0 = a * Wc[lane * 2 + 0] + b * Wc[(lane + 64) * 2 + 0];
    float l1 = a * Wc[lane * 2 + 1] + b * Wc[(lane + 64) * 2 + 1];
#pragma unroll
    for (int off = 32; off; off >>= 1) {
        l0 += __shfl_down(l0, off, 64);
        l1 += __shfl_down(l1, off, 64);
    }
    if (lane == 0) {
        logits[(size_t)node * 2 + 0] = l0 + bc[0];
        logits[(size_t)node * 2 + 1] = l1 + bc[1];
    }
}

// ===========================================================================
extern "C" void kernel_launch(void* const* d_in, const int* in_sizes, int n_in,
                              void* d_out, int out_size, void* d_ws, size_t ws_size,
                              hipStream_t stream) {
    const float* x    = (const float*)d_in[0];
    const int*   ei   = (const int*)d_in[1];
    const int*   src  = ei;
    const int*   dstp = ei + N_EDGES;

    const float* W1l = (const float*)d_in[2];
    const float* W1r = (const float*)d_in[3];
    const float* b1  = (const float*)d_in[4];
    const float* g1  = (const float*)d_in[5];
    const float* bb1 = (const float*)d_in[6];
    const float* m1  = (const float*)d_in[7];
    const float* v1  = (const float*)d_in[8];

    const float* W2l = (const float*)d_in[9];
    const float* W2r = (const float*)d_in[10];
    const float* b2  = (const float*)d_in[11];
    const float* g2  = (const float*)d_in[12];
    const float* bb2 = (const float*)d_in[13];
    const float* m2  = (const float*)d_in[14];
    const float* v2  = (const float*)d_in[15];

    const float* W3l = (const float*)d_in[16];
    const float* W3r = (const float*)d_in[17];
    const float* b3  = (const float*)d_in[18];
    const float* g3  = (const float*)d_in[19];
    const float* bb3 = (const float*)d_in[20];
    const float* m3  = (const float*)d_in[21];
    const float* v3  = (const float*)d_in[22];

    const float* Wc = (const float*)d_in[23];
    const float* bc = (const float*)d_in[24];

    // workspace layout (4-byte base units; wf arrays are ushort)
    float* inv   = (float*)d_ws;                        // N
    int*   deg   = (int*)(inv + N_NODES);               // N
    int*   offs  = deg + N_NODES;                       // N+1
    int*   cursor= offs + N_NODES + 1;                  // N
    int*   adj   = cursor + N_NODES;                    // E
    int*   bsum  = adj + N_EDGES;                       // 512
    unsigned short* wf2h = (unsigned short*)(bsum + 512);  // 16384
    unsigned short* wf2l = wf2h + 16384;                   // 16384
    unsigned short* wf3h = wf2l + 16384;                   // 32768
    unsigned short* wf3l = wf3h + 32768;                   // 32768
    float* agg   = (float*)(wf3l + 32768);              // N*128 (mean buffer)
    float* h1    = agg + (size_t)N_NODES * 128;         // N*64
    float* h2    = h1 + (size_t)N_NODES * 64;           // N*128

    float* emb    = (float*)d_out;
    float* logits = emb + (size_t)N_NODES * 128;

    const int B = 256;
    const int nb = (N_NODES + 255) / 256;               // 391 <= 512
    const int nMfBlocks = (N_NODES + 127) / 128;        // 782
    const int nWaveBlocks = ((size_t)N_NODES * 64 + B - 1) / B;

    // ---- CSR build + weight pre-swizzle (independent of layer outputs) ----
    hipMemsetAsync(deg, 0, N_NODES * sizeof(int), stream);
    k_deg<<<(N_EDGES + B - 1) / B, B, 0, stream>>>(dstp, deg, N_EDGES);
    k_scan1<<<nb, 256, 0, stream>>>(deg, offs, bsum, N_NODES);
    k_scan2<<<1, 512, 0, stream>>>(bsum, nb);
    k_prep<<<nb, 256, 0, stream>>>(offs, bsum, deg, cursor, inv, N_NODES, N_EDGES);
    k_fill<<<(N_EDGES + B - 1) / B, B, 0, stream>>>(src, dstp, cursor, adj, N_EDGES);
    k_wprep<64><<<(128 * 128) / 256, 256, 0, stream>>>(W2l, W2r, wf2h, wf2l);
    k_wprep<128><<<(256 * 128) / 256, 256, 0, stream>>>(W3l, W3r, wf3h, wf3l);

    // ---- layer 1: 10 -> 64, ReLU ----
    k_gather10<<<nWaveBlocks, B, 0, stream>>>(x, adj, offs, inv, agg, N_NODES);
    k_linear<10, 64, true><<<((size_t)N_NODES * 64 + B - 1) / B, B, 0, stream>>>(
        x, agg, W1l, W1r, b1, g1, bb1, m1, v1, h1, N_NODES);

    // ---- layer 2: 64 -> 128, ReLU ----
    k_gather64<<<nWaveBlocks, B, 0, stream>>>(h1, adj, offs, inv, agg, N_NODES);
    k_linear_mfma<64, true><<<nMfBlocks, 256, 0, stream>>>(
        h1, agg, wf2h, wf2l, b2, g2, bb2, m2, v2, h2, N_NODES);

    // ---- layer 3: 128 -> 128, no ReLU, into d_out emb region ----
    k_gather128<<<nWaveBlocks, B, 0, stream>>>(h2, adj, offs, inv, agg, N_NODES);
    k_linear_mfma<128, false><<<nMfBlocks, 256, 0, stream>>>(
        h2, agg, wf3h, wf3l, b3, g3, bb3, m3, v3, emb, N_NODES);

    // ---- normalize + logits ----
    k_norm_logits<<<nWaveBlocks, B, 0, stream>>>(emb, logits, Wc, bc, N_NODES);
}